// Round 13
// baseline (559.919 us; speedup 1.0000x reference)
//
#include <hip/hip_runtime.h>
#include <math.h>

#define NOSC 2048
#define NB 16
#define DT 0.1f
#define M_TOT (NB * NOSC)    // 32768
#define KTP 2056             // padded LDS K row
#define NBLK_P 128           // persistent blocks (1 per CU on half the GPU)

typedef __attribute__((ext_vector_type(8))) short bf16x8;
typedef __attribute__((ext_vector_type(4))) float f32x4;

__device__ __forceinline__ unsigned short f2bf(float x) {
    unsigned int u = __float_as_uint(x);
    u += 0x7FFFu + ((u >> 16) & 1u);          // round-to-nearest-even
    return (unsigned short)(u >> 16);
}
__device__ __forceinline__ float bf2f(unsigned short u) {
    return __uint_as_float(((unsigned int)u) << 16);
}

// ---- agent-scope (cross-XCD coherent, L3) helpers ----
__device__ __forceinline__ bf16x8 loadR16(const unsigned short* p) {
    union { unsigned int u[4]; bf16x8 v; } x;
#pragma unroll
    for (int e = 0; e < 4; ++e)
        x.u[e] = __hip_atomic_load((unsigned int*)p + e,
                                   __ATOMIC_RELAXED, __HIP_MEMORY_SCOPE_AGENT);
    return x.v;
}
__device__ __forceinline__ void storeU32(unsigned short* p, unsigned int v) {
    __hip_atomic_store((unsigned int*)p, v,
                       __ATOMIC_RELAXED, __HIP_MEMORY_SCOPE_AGENT);
}

// lean grid barrier: counter cnt used once per kernel run (zeroed by zero_kernel)
__device__ __forceinline__ void gbar(unsigned int* cnt, int t) {
    __threadfence();            // own stores visible at agent scope
    __syncthreads();            // all threads' stores drained (vmcnt 0)
    if (t == 0) {
        __hip_atomic_fetch_add(cnt, 1u, __ATOMIC_ACQ_REL, __HIP_MEMORY_SCOPE_AGENT);
        while (__hip_atomic_load(cnt, __ATOMIC_ACQUIRE, __HIP_MEMORY_SCOPE_AGENT) < NBLK_P)
            __builtin_amdgcn_s_sleep(2);
    }
    __syncthreads();
}

// ws layout:
//   persistent path: [cnt 11 u32][accum 32 f32] at base (176 B)
//   fallback path:   Kb[2048][2048] bf16 at base (8 MB)  (overlaps cnt/accum - never coexist)
//   both: RA / RB bf16 R-buffers at base + 8 MB (128 KB each)

__global__ void zero_kernel(unsigned int* cnt, float* accum) {
    const int t = threadIdx.x;
    if (t < 11) cnt[t] = 0u;
    if (t < 32) accum[t] = 0.0f;
}

// ---------------- persistent cooperative kernel ----------------
// 128 blocks x 1024 thr. Block owns i in [bx*16, bx*16+16).
// K tile in LDS for ALL steps; theta/sin/cos in registers; R via agent atomics.
__global__ __launch_bounds__(1024, 4) void mega_kernel(
    const float* __restrict__ theta_in,
    const float* __restrict__ Kmat,
    const float* __restrict__ omega,
    const float* __restrict__ kg,
    const float* __restrict__ mod,
    float* __restrict__ th,
    float* __restrict__ coh,
    unsigned short* __restrict__ RA,
    unsigned short* __restrict__ RB,
    unsigned int* __restrict__ cnt,
    float* __restrict__ accum)
{
    __shared__ unsigned short Kt[16][KTP];          // 64.25 KB, persistent
    __shared__ float part[16][2][64][4];            // 32 KB
    __shared__ float coup[32][16];                  // 2 KB

    const int t = threadIdx.x;
    const int lane = t & 63;
    const int w = t >> 6;                            // wave = k-sixteenth
    const int i0 = blockIdx.x * 16;
    const int rl = lane & 15;
    const int kbase = w * 128 + ((lane >> 4) << 3);

    // ---- one-time: convert own K tile (16 rows, 128 KB fp32 contiguous) to LDS
    {
        const float4* __restrict__ src =
            reinterpret_cast<const float4*>(Kmat + (size_t)i0 * NOSC);
#pragma unroll
        for (int p = 0; p < 8; ++p) {
            const int q = t + p * 1024;              // float4 index 0..8191
            float4 v = src[q];
            ushort4 u = {f2bf(v.x), f2bf(v.y), f2bf(v.z), f2bf(v.w)};
            *reinterpret_cast<ushort4*>(&Kt[q >> 9][(q & 511) * 4]) = u;
        }
    }

    // ---- one-time: own theta state into registers, publish R0
    float th_o = 0.0f, sin_i = 0.0f, cos_i = 0.0f, om_i = 0.0f;
    float ws = 0.0f, wc = 0.0f;
    size_t o_upd = 0; int b2 = 0, il = 0;
    if (t < 256) {
        b2 = t >> 4; il = t & 15;
        o_upd = (size_t)b2 * NOSC + i0 + il;
        om_i = omega[i0 + il];
        th_o = theta_in[o_upd];
        sincosf(th_o, &sin_i, &cos_i);
        float sn = __shfl_down(sin_i, 1), cn = __shfl_down(cos_i, 1);
        if ((il & 1) == 0) {
            storeU32(RA + o_upd, (unsigned)f2bf(sin_i) | ((unsigned)f2bf(sn) << 16));
            storeU32(RA + M_TOT + o_upd, (unsigned)f2bf(cos_i) | ((unsigned)f2bf(cn) << 16));
        }
    }
    const float scale = kg[0] * (1.0f + mod[0]) * (1.0f / (float)NOSC);

    gbar(&cnt[0], t);           // R0 complete everywhere (also covers Kt)

    const unsigned short* Rcur = RA;
    unsigned short* Rnxt = RB;

    for (int s = 0; s < 10; ++s) {
        // A fragments (agent loads from L3), B from LDS
        bf16x8 as[4], ac[4], bb[4];
        const unsigned short* pas = Rcur + (size_t)rl * NOSC + kbase;
        const unsigned short* pac = Rcur + (size_t)(16 + rl) * NOSC + kbase;
#pragma unroll
        for (int k = 0; k < 4; ++k) {
            as[k] = loadR16(pas + k * 32);
            ac[k] = loadR16(pac + k * 32);
            bb[k] = *reinterpret_cast<const bf16x8*>(&Kt[rl][kbase + k * 32]);
        }
        f32x4 acc_s = {0.0f, 0.0f, 0.0f, 0.0f};
        f32x4 acc_c = {0.0f, 0.0f, 0.0f, 0.0f};
#pragma unroll
        for (int k = 0; k < 4; ++k) {
            acc_s = __builtin_amdgcn_mfma_f32_16x16x32_bf16(as[k], bb[k], acc_s, 0, 0, 0);
            acc_c = __builtin_amdgcn_mfma_f32_16x16x32_bf16(ac[k], bb[k], acc_c, 0, 0, 0);
        }
        *reinterpret_cast<f32x4*>(&part[w][0][lane][0]) = acc_s;
        *reinterpret_cast<f32x4*>(&part[w][1][lane][0]) = acc_c;
        __syncthreads();

        if (t < 512) {                               // reduce 16 k-partials
            const int c = t >> 4, ilr = t & 15;
            const int half = c >> 4, cl = c & 15;
            const int ln = ((cl >> 2) << 4) | ilr, rg = cl & 3;
            float sum = 0.0f;
#pragma unroll
            for (int q = 0; q < 16; ++q) sum += part[q][half][ln][rg];
            coup[c][ilr] = sum;
        }
        __syncthreads();

        if (t < 256) {                               // theta update (in-register)
            const float aS = coup[b2][il];
            const float aC = coup[16 + b2][il];
            float nt = th_o + DT * (om_i + scale * (cos_i * aS - sin_i * aC));
            sincosf(nt, &ws, &wc);
            if (s == 9) {
                th[o_upd] = atan2f(ws, wc);          // final wrap to (-pi, pi]
            } else {
                // wrap only shifts by 2*pi*k -> sin/cos unchanged; defer atan2
                th_o = nt; sin_i = ws; cos_i = wc;
                float sn = __shfl_down(ws, 1), cn = __shfl_down(wc, 1);
                if ((il & 1) == 0) {
                    storeU32(Rnxt + o_upd, (unsigned)f2bf(ws) | ((unsigned)f2bf(sn) << 16));
                    storeU32(Rnxt + M_TOT + o_upd, (unsigned)f2bf(wc) | ((unsigned)f2bf(cn) << 16));
                }
            }
        }
        if (s < 9) {
            gbar(&cnt[s + 1], t);
            const unsigned short* tmp = Rcur;
            Rcur = Rnxt; Rnxt = (unsigned short*)tmp;
        }
    }

    // ---- fused coherence: sum final ws/wc over this block's 16 i per batch
    if (t < 256) {
#pragma unroll
        for (int m = 1; m < 16; m <<= 1) {
            ws += __shfl_xor(ws, m);
            wc += __shfl_xor(wc, m);
        }
        if (il == 0) {
            __hip_atomic_fetch_add(&accum[b2], ws, __ATOMIC_RELAXED, __HIP_MEMORY_SCOPE_AGENT);
            __hip_atomic_fetch_add(&accum[16 + b2], wc, __ATOMIC_RELAXED, __HIP_MEMORY_SCOPE_AGENT);
        }
    }
    gbar(&cnt[10], t);
    if (blockIdx.x == 0 && t < 16) {
        float ss = __hip_atomic_load(&accum[t], __ATOMIC_RELAXED, __HIP_MEMORY_SCOPE_AGENT)
                   * (1.0f / (float)NOSC);
        float cc = __hip_atomic_load(&accum[16 + t], __ATOMIC_RELAXED, __HIP_MEMORY_SCOPE_AGENT)
                   * (1.0f / (float)NOSC);
        coh[t] = sqrtf(ss * ss + cc * cc);
    }
}

// ---------------- fallback: round-11 multi-dispatch path ----------------
__global__ void init_kernel(const float* __restrict__ th_in,
                            float* __restrict__ th,
                            unsigned short* __restrict__ R0) {
    const int o4 = (blockIdx.x * 256 + threadIdx.x) * 4;
    if (o4 < M_TOT) {
        float4 v = *reinterpret_cast<const float4*>(th_in + o4);
        *reinterpret_cast<float4*>(th + o4) = v;
        float s0, c0, s1, c1, s2, c2, s3, c3;
        sincosf(v.x, &s0, &c0); sincosf(v.y, &s1, &c1);
        sincosf(v.z, &s2, &c2); sincosf(v.w, &s3, &c3);
        ushort4 us = {f2bf(s0), f2bf(s1), f2bf(s2), f2bf(s3)};
        ushort4 uc = {f2bf(c0), f2bf(c1), f2bf(c2), f2bf(c3)};
        *reinterpret_cast<ushort4*>(R0 + o4) = us;
        *reinterpret_cast<ushort4*>(R0 + M_TOT + o4) = uc;
    }
}

template <bool FIRST, bool FINAL>
__global__ __launch_bounds__(1024, 4) void step_kernel(
    const float* __restrict__ Kmat,
    unsigned short* __restrict__ Kb,
    const unsigned short* __restrict__ Rc,
    unsigned short* __restrict__ Rn,
    const float* __restrict__ omega,
    const float* __restrict__ kg,
    const float* __restrict__ mod,
    float* __restrict__ th)
{
    __shared__ float part[16][2][64][4];
    __shared__ float coup[32][16];

    const int t = threadIdx.x;
    const int lane = t & 63;
    const int w = t >> 6;
    const int i0 = blockIdx.x * 16;

    float th_o = 0.0f, sin_i = 0.0f, cos_i = 0.0f, om_i = 0.0f;
    size_t o_upd = 0;
    if (t < 256) {
        const int b2 = t >> 4;
        const int il = t & 15;
        o_upd = (size_t)b2 * NOSC + i0 + il;
        th_o = th[o_upd];
        sin_i = bf2f(Rc[o_upd]);
        cos_i = bf2f(Rc[M_TOT + o_upd]);
        om_i = omega[i0 + il];
    }
    const float scale = kg[0] * (1.0f + mod[0]) * (1.0f / (float)NOSC);

    const int rl = lane & 15;
    const int kbase = w * 128 + ((lane >> 4) << 3);
    const unsigned short* __restrict__ pas = Rc + (size_t)rl * NOSC + kbase;
    const unsigned short* __restrict__ pac = Rc + (size_t)(16 + rl) * NOSC + kbase;

    bf16x8 as[4], ac[4], bb[4];
    if constexpr (FIRST) {
        __shared__ unsigned short Kt[16][KTP];
        const float4* __restrict__ src =
            reinterpret_cast<const float4*>(Kmat + (size_t)i0 * NOSC);
#pragma unroll
        for (int p = 0; p < 8; ++p) {
            const int q = t + p * 1024;
            float4 v = src[q];
            ushort4 u = {f2bf(v.x), f2bf(v.y), f2bf(v.z), f2bf(v.w)};
            const int row = q >> 9;
            const int col = (q & 511) * 4;
            *reinterpret_cast<ushort4*>(&Kt[row][col]) = u;
            *reinterpret_cast<ushort4*>(Kb + (size_t)(i0 + row) * NOSC + col) = u;
        }
        __syncthreads();
#pragma unroll
        for (int k = 0; k < 4; ++k)
            bb[k] = *reinterpret_cast<const bf16x8*>(&Kt[rl][kbase + k * 32]);
    } else {
        const unsigned short* __restrict__ pbg = Kb + (size_t)(i0 + rl) * NOSC + kbase;
#pragma unroll
        for (int k = 0; k < 4; ++k)
            bb[k] = *reinterpret_cast<const bf16x8*>(pbg + k * 32);
    }
#pragma unroll
    for (int k = 0; k < 4; ++k) {
        as[k] = *reinterpret_cast<const bf16x8*>(pas + k * 32);
        ac[k] = *reinterpret_cast<const bf16x8*>(pac + k * 32);
    }

    f32x4 acc_s = {0.0f, 0.0f, 0.0f, 0.0f};
    f32x4 acc_c = {0.0f, 0.0f, 0.0f, 0.0f};
#pragma unroll
    for (int k = 0; k < 4; ++k) {
        acc_s = __builtin_amdgcn_mfma_f32_16x16x32_bf16(as[k], bb[k], acc_s, 0, 0, 0);
        acc_c = __builtin_amdgcn_mfma_f32_16x16x32_bf16(ac[k], bb[k], acc_c, 0, 0, 0);
    }
    *reinterpret_cast<f32x4*>(&part[w][0][lane][0]) = acc_s;
    *reinterpret_cast<f32x4*>(&part[w][1][lane][0]) = acc_c;
    __syncthreads();

    if (t < 512) {
        const int c = t >> 4, il = t & 15;
        const int half = c >> 4, cl = c & 15;
        const int ln = ((cl >> 2) << 4) | il, rg = cl & 3;
        float s = 0.0f;
#pragma unroll
        for (int q = 0; q < 16; ++q) s += part[q][half][ln][rg];
        coup[c][il] = s;
    }
    __syncthreads();

    if (t < 256) {
        const int b2 = t >> 4;
        const int il = t & 15;
        const float aS = coup[b2][il];
        const float aC = coup[16 + b2][il];
        float nt = th_o + DT * (om_i + scale * (cos_i * aS - sin_i * aC));
        float ws, wc;
        sincosf(nt, &ws, &wc);
        th[o_upd] = FINAL ? atan2f(ws, wc) : nt;
        Rn[o_upd] = f2bf(ws);
        Rn[M_TOT + o_upd] = f2bf(wc);
    }
}

__global__ void coherence_kernel(const unsigned short* __restrict__ R,
                                 float* __restrict__ coh) {
    const int b = blockIdx.x;
    const int t = threadIdx.x;
    float ss = 0.0f, sc = 0.0f;
    for (int j = t; j < NOSC; j += 256) {
        ss += bf2f(R[(size_t)b * NOSC + j]);
        sc += bf2f(R[M_TOT + (size_t)b * NOSC + j]);
    }
    for (int off = 32; off > 0; off >>= 1) {
        ss += __shfl_down(ss, off);
        sc += __shfl_down(sc, off);
    }
    __shared__ float red[8];
    const int w = t >> 6;
    if ((t & 63) == 0) { red[w * 2] = sc; red[w * 2 + 1] = ss; }
    __syncthreads();
    if (t == 0) {
        float tc = 0.0f, ts = 0.0f;
        for (int k = 0; k < 4; ++k) { tc += red[k * 2]; ts += red[k * 2 + 1]; }
        tc /= (float)NOSC;
        ts /= (float)NOSC;
        coh[b] = sqrtf(tc * tc + ts * ts);
    }
}

extern "C" void kernel_launch(void* const* d_in, const int* in_sizes, int n_in,
                              void* d_out, int out_size, void* d_ws, size_t ws_size,
                              hipStream_t stream) {
    const float* theta_in = (const float*)d_in[0];
    const float* Kmat     = (const float*)d_in[1];
    const float* omega    = (const float*)d_in[2];
    const float* kg       = (const float*)d_in[3];
    const float* mod      = (const float*)d_in[4];

    float* th  = (float*)d_out;               // [NB][NOSC] final theta
    float* coh = (float*)d_out + M_TOT;       // [NB]

    // persistent-path control block at ws base (overlaps fallback's Kb — exclusive)
    unsigned int* cnt = (unsigned int*)d_ws;              // 11 u32
    float* accum = (float*)d_ws + 16;                     // 32 f32
    unsigned short* Kb = (unsigned short*)d_ws;           // 8 MB (fallback only)
    unsigned short* RA = (unsigned short*)d_ws + (size_t)NOSC * NOSC; // 128 KB
    unsigned short* RB = RA + 2 * M_TOT;                              // 128 KB

    zero_kernel<<<1, 64, 0, stream>>>(cnt, accum);

    void* args[] = {(void*)&theta_in, (void*)&Kmat, (void*)&omega,
                    (void*)&kg, (void*)&mod, (void*)&th, (void*)&coh,
                    (void*)&RA, (void*)&RB, (void*)&cnt, (void*)&accum};
    hipError_t err = hipLaunchCooperativeKernel((const void*)mega_kernel,
                                                dim3(NBLK_P), dim3(1024),
                                                args, 0, stream);
    if (err != hipSuccess) {
        // fallback: proven round-11 multi-dispatch path (overwrites cnt region as Kb)
        init_kernel<<<32, 256, 0, stream>>>(theta_in, th, RA);
        for (int s = 0; s < 10; ++s) {
            const unsigned short* rc = (s & 1) ? RB : RA;
            unsigned short* rn = (s & 1) ? RA : RB;
            if (s == 0)
                step_kernel<true, false><<<NOSC / 16, 1024, 0, stream>>>(
                    Kmat, Kb, rc, rn, omega, kg, mod, th);
            else if (s < 9)
                step_kernel<false, false><<<NOSC / 16, 1024, 0, stream>>>(
                    Kmat, Kb, rc, rn, omega, kg, mod, th);
            else
                step_kernel<false, true><<<NOSC / 16, 1024, 0, stream>>>(
                    Kmat, Kb, rc, rn, omega, kg, mod, th);
        }
        coherence_kernel<<<NB, 256, 0, stream>>>(RA, coh);
    }
}

// Round 14
// 146.981 us; speedup vs baseline: 3.8095x; 3.8095x over previous
//
#include <hip/hip_runtime.h>
#include <math.h>

#define NOSC 2048
#define NB 16
#define DT 0.1f
#define M_TOT (NB * NOSC)    // 32768
#define KTP 2056             // padded LDS K row
#define NBLK_P 128           // persistent blocks (1 per CU, half the GPU)

typedef __attribute__((ext_vector_type(8))) short bf16x8;
typedef __attribute__((ext_vector_type(4))) float f32x4;

__device__ __forceinline__ unsigned short f2bf(float x) {
    unsigned int u = __float_as_uint(x);
    u += 0x7FFFu + ((u >> 16) & 1u);          // round-to-nearest-even
    return (unsigned short)(u >> 16);
}
__device__ __forceinline__ float bf2f(unsigned short u) {
    return __uint_as_float(((unsigned int)u) << 16);
}

// ---- agent-scope RELAXED helpers (sc1: bypass L2, coherent at L3; no fences) ----
__device__ __forceinline__ bf16x8 loadR16(const unsigned short* p) {
    union { unsigned long long u[2]; bf16x8 v; } x;
    x.u[0] = __hip_atomic_load((const unsigned long long*)p,
                               __ATOMIC_RELAXED, __HIP_MEMORY_SCOPE_AGENT);
    x.u[1] = __hip_atomic_load((const unsigned long long*)p + 1,
                               __ATOMIC_RELAXED, __HIP_MEMORY_SCOPE_AGENT);
    return x.v;
}
__device__ __forceinline__ void storeU32(unsigned short* p, unsigned int v) {
    __hip_atomic_store((unsigned int*)p, v,
                       __ATOMIC_RELAXED, __HIP_MEMORY_SCOPE_AGENT);
}

// Fence-free grid barrier. Valid because ALL cross-block data moves via
// agent-scope relaxed (sc1) accesses that never live in L1/L2:
//   release = s_waitcnt vmcnt(0) (sc1 stores retired => visible at L3)
//   arrival/poll = RELAXED atomics (no buffer_inv / wbl2 storms — round 13's bug)
__device__ __forceinline__ void gbar(unsigned int* cnt, int t) {
    asm volatile("s_waitcnt vmcnt(0)" ::: "memory");   // each thread's stores done
    __syncthreads();                                   // whole block released
    if (t == 0) {
        __hip_atomic_fetch_add(cnt, 1u, __ATOMIC_RELAXED, __HIP_MEMORY_SCOPE_AGENT);
        while (__hip_atomic_load(cnt, __ATOMIC_RELAXED, __HIP_MEMORY_SCOPE_AGENT) < NBLK_P)
            __builtin_amdgcn_s_sleep(1);
    }
    __syncthreads();
}

// ws layout:
//   persistent path: [cnt 11 u32][pad][accum 32 f32] at base
//   fallback path:   Kb[2048][2048] bf16 at base (8 MB) — paths never coexist
//   both: RA / RB bf16 R-buffers at base + 8 MB (128 KB each)

__global__ void zero_kernel(unsigned int* cnt, float* accum) {
    const int t = threadIdx.x;
    if (t < 11) cnt[t] = 0u;
    if (t < 32) accum[t] = 0.0f;
}

// ---------------- persistent cooperative kernel ----------------
// 128 blocks x 1024 thr. Block owns i in [bx*16, bx*16+16).
// K tile in LDS for ALL steps; theta/sin/cos in registers; R via L3 atomics.
__global__ __launch_bounds__(1024, 4) void mega_kernel(
    const float* __restrict__ theta_in,
    const float* __restrict__ Kmat,
    const float* __restrict__ omega,
    const float* __restrict__ kg,
    const float* __restrict__ mod,
    float* __restrict__ th,
    float* __restrict__ coh,
    unsigned short* __restrict__ RA,
    unsigned short* __restrict__ RB,
    unsigned int* __restrict__ cnt,
    float* __restrict__ accum)
{
    __shared__ unsigned short Kt[16][KTP];          // 64.25 KB, persistent
    __shared__ float part[16][2][64][4];            // 32 KB
    __shared__ float coup[32][16];                  // 2 KB

    const int t = threadIdx.x;
    const int lane = t & 63;
    const int w = t >> 6;                            // wave = k-sixteenth
    const int i0 = blockIdx.x * 16;
    const int rl = lane & 15;
    const int kbase = w * 128 + ((lane >> 4) << 3);

    // ---- one-time: convert own K tile (16 rows, 128 KB fp32 contiguous) to LDS
    {
        const float4* __restrict__ src =
            reinterpret_cast<const float4*>(Kmat + (size_t)i0 * NOSC);
#pragma unroll
        for (int p = 0; p < 8; ++p) {
            const int q = t + p * 1024;              // float4 index 0..8191
            float4 v = src[q];
            ushort4 u = {f2bf(v.x), f2bf(v.y), f2bf(v.z), f2bf(v.w)};
            *reinterpret_cast<ushort4*>(&Kt[q >> 9][(q & 511) * 4]) = u;
        }
    }

    // ---- one-time: own theta state into registers, publish R0
    float th_o = 0.0f, sin_i = 0.0f, cos_i = 0.0f, om_i = 0.0f;
    float ws = 0.0f, wc = 0.0f;
    size_t o_upd = 0; int b2 = 0, il = 0;
    if (t < 256) {
        b2 = t >> 4; il = t & 15;
        o_upd = (size_t)b2 * NOSC + i0 + il;
        om_i = omega[i0 + il];
        th_o = theta_in[o_upd];
        sincosf(th_o, &sin_i, &cos_i);
        float sn = __shfl_down(sin_i, 1), cn = __shfl_down(cos_i, 1);
        if ((il & 1) == 0) {
            storeU32(RA + o_upd, (unsigned)f2bf(sin_i) | ((unsigned)f2bf(sn) << 16));
            storeU32(RA + M_TOT + o_upd, (unsigned)f2bf(cos_i) | ((unsigned)f2bf(cn) << 16));
        }
    }
    const float scale = kg[0] * (1.0f + mod[0]) * (1.0f / (float)NOSC);

    gbar(&cnt[0], t);           // R0 complete everywhere

    const unsigned short* Rcur = RA;
    unsigned short* Rnxt = RB;

    for (int s = 0; s < 10; ++s) {
        // A fragments (relaxed L3 loads), B from LDS
        bf16x8 as[4], ac[4], bb[4];
        const unsigned short* pas = Rcur + (size_t)rl * NOSC + kbase;
        const unsigned short* pac = Rcur + (size_t)(16 + rl) * NOSC + kbase;
#pragma unroll
        for (int k = 0; k < 4; ++k) {
            as[k] = loadR16(pas + k * 32);
            ac[k] = loadR16(pac + k * 32);
            bb[k] = *reinterpret_cast<const bf16x8*>(&Kt[rl][kbase + k * 32]);
        }
        f32x4 acc_s = {0.0f, 0.0f, 0.0f, 0.0f};
        f32x4 acc_c = {0.0f, 0.0f, 0.0f, 0.0f};
#pragma unroll
        for (int k = 0; k < 4; ++k) {
            acc_s = __builtin_amdgcn_mfma_f32_16x16x32_bf16(as[k], bb[k], acc_s, 0, 0, 0);
            acc_c = __builtin_amdgcn_mfma_f32_16x16x32_bf16(ac[k], bb[k], acc_c, 0, 0, 0);
        }
        *reinterpret_cast<f32x4*>(&part[w][0][lane][0]) = acc_s;
        *reinterpret_cast<f32x4*>(&part[w][1][lane][0]) = acc_c;
        __syncthreads();

        if (t < 512) {                               // reduce 16 k-partials
            const int c = t >> 4, ilr = t & 15;
            const int half = c >> 4, cl = c & 15;
            const int ln = ((cl >> 2) << 4) | ilr, rg = cl & 3;
            float sum = 0.0f;
#pragma unroll
            for (int q = 0; q < 16; ++q) sum += part[q][half][ln][rg];
            coup[c][ilr] = sum;
        }
        __syncthreads();

        if (t < 256) {                               // theta update (in-register)
            const float aS = coup[b2][il];
            const float aC = coup[16 + b2][il];
            float nt = th_o + DT * (om_i + scale * (cos_i * aS - sin_i * aC));
            sincosf(nt, &ws, &wc);
            if (s == 9) {
                th[o_upd] = atan2f(ws, wc);          // final wrap to (-pi, pi]
            } else {
                // wrap only shifts by 2*pi*k -> sin/cos unchanged; defer atan2
                th_o = nt; sin_i = ws; cos_i = wc;
                float sn = __shfl_down(ws, 1), cn = __shfl_down(wc, 1);
                if ((il & 1) == 0) {
                    storeU32(Rnxt + o_upd, (unsigned)f2bf(ws) | ((unsigned)f2bf(sn) << 16));
                    storeU32(Rnxt + M_TOT + o_upd, (unsigned)f2bf(wc) | ((unsigned)f2bf(cn) << 16));
                }
            }
        }
        if (s < 9) {
            gbar(&cnt[s + 1], t);
            const unsigned short* tmp = Rcur;
            Rcur = Rnxt; Rnxt = (unsigned short*)tmp;
        }
    }

    // ---- fused coherence: sum final ws/wc over this block's 16 i per batch
    if (t < 256) {
#pragma unroll
        for (int m = 1; m < 16; m <<= 1) {
            ws += __shfl_xor(ws, m);
            wc += __shfl_xor(wc, m);
        }
        if (il == 0) {
            __hip_atomic_fetch_add(&accum[b2], ws, __ATOMIC_RELAXED, __HIP_MEMORY_SCOPE_AGENT);
            __hip_atomic_fetch_add(&accum[16 + b2], wc, __ATOMIC_RELAXED, __HIP_MEMORY_SCOPE_AGENT);
        }
    }
    gbar(&cnt[10], t);
    if (blockIdx.x == 0 && t < 16) {
        float ss = __hip_atomic_load(&accum[t], __ATOMIC_RELAXED, __HIP_MEMORY_SCOPE_AGENT)
                   * (1.0f / (float)NOSC);
        float cc = __hip_atomic_load(&accum[16 + t], __ATOMIC_RELAXED, __HIP_MEMORY_SCOPE_AGENT)
                   * (1.0f / (float)NOSC);
        coh[t] = sqrtf(ss * ss + cc * cc);
    }
}

// ---------------- fallback: round-11-style multi-dispatch path ----------------
__global__ void init_kernel(const float* __restrict__ th_in,
                            float* __restrict__ th,
                            unsigned short* __restrict__ R0) {
    const int o4 = (blockIdx.x * 256 + threadIdx.x) * 4;
    if (o4 < M_TOT) {
        float4 v = *reinterpret_cast<const float4*>(th_in + o4);
        *reinterpret_cast<float4*>(th + o4) = v;
        float s0, c0, s1, c1, s2, c2, s3, c3;
        sincosf(v.x, &s0, &c0); sincosf(v.y, &s1, &c1);
        sincosf(v.z, &s2, &c2); sincosf(v.w, &s3, &c3);
        ushort4 us = {f2bf(s0), f2bf(s1), f2bf(s2), f2bf(s3)};
        ushort4 uc = {f2bf(c0), f2bf(c1), f2bf(c2), f2bf(c3)};
        *reinterpret_cast<ushort4*>(R0 + o4) = us;
        *reinterpret_cast<ushort4*>(R0 + M_TOT + o4) = uc;
    }
}

template <bool FIRST, bool FINAL>
__global__ __launch_bounds__(1024, 4) void step_kernel(
    const float* __restrict__ Kmat,
    unsigned short* __restrict__ Kb,
    const unsigned short* __restrict__ Rc,
    unsigned short* __restrict__ Rn,
    const float* __restrict__ omega,
    const float* __restrict__ kg,
    const float* __restrict__ mod,
    float* __restrict__ th)
{
    __shared__ float part[16][2][64][4];
    __shared__ float coup[32][16];

    const int t = threadIdx.x;
    const int lane = t & 63;
    const int w = t >> 6;
    const int i0 = blockIdx.x * 16;

    float th_o = 0.0f, sin_i = 0.0f, cos_i = 0.0f, om_i = 0.0f;
    size_t o_upd = 0;
    if (t < 256) {
        const int b2 = t >> 4;
        const int il = t & 15;
        o_upd = (size_t)b2 * NOSC + i0 + il;
        th_o = th[o_upd];
        sin_i = bf2f(Rc[o_upd]);
        cos_i = bf2f(Rc[M_TOT + o_upd]);
        om_i = omega[i0 + il];
    }
    const float scale = kg[0] * (1.0f + mod[0]) * (1.0f / (float)NOSC);

    const int rl = lane & 15;
    const int kbase = w * 128 + ((lane >> 4) << 3);
    const unsigned short* __restrict__ pas = Rc + (size_t)rl * NOSC + kbase;
    const unsigned short* __restrict__ pac = Rc + (size_t)(16 + rl) * NOSC + kbase;

    bf16x8 as[4], ac[4], bb[4];
    if constexpr (FIRST) {
        __shared__ unsigned short Kt[16][KTP];
        const float4* __restrict__ src =
            reinterpret_cast<const float4*>(Kmat + (size_t)i0 * NOSC);
#pragma unroll
        for (int p = 0; p < 8; ++p) {
            const int q = t + p * 1024;
            float4 v = src[q];
            ushort4 u = {f2bf(v.x), f2bf(v.y), f2bf(v.z), f2bf(v.w)};
            const int row = q >> 9;
            const int col = (q & 511) * 4;
            *reinterpret_cast<ushort4*>(&Kt[row][col]) = u;
            *reinterpret_cast<ushort4*>(Kb + (size_t)(i0 + row) * NOSC + col) = u;
        }
        __syncthreads();
#pragma unroll
        for (int k = 0; k < 4; ++k)
            bb[k] = *reinterpret_cast<const bf16x8*>(&Kt[rl][kbase + k * 32]);
    } else {
        const unsigned short* __restrict__ pbg = Kb + (size_t)(i0 + rl) * NOSC + kbase;
#pragma unroll
        for (int k = 0; k < 4; ++k)
            bb[k] = *reinterpret_cast<const bf16x8*>(pbg + k * 32);
    }
#pragma unroll
    for (int k = 0; k < 4; ++k) {
        as[k] = *reinterpret_cast<const bf16x8*>(pas + k * 32);
        ac[k] = *reinterpret_cast<const bf16x8*>(pac + k * 32);
    }

    f32x4 acc_s = {0.0f, 0.0f, 0.0f, 0.0f};
    f32x4 acc_c = {0.0f, 0.0f, 0.0f, 0.0f};
#pragma unroll
    for (int k = 0; k < 4; ++k) {
        acc_s = __builtin_amdgcn_mfma_f32_16x16x32_bf16(as[k], bb[k], acc_s, 0, 0, 0);
        acc_c = __builtin_amdgcn_mfma_f32_16x16x32_bf16(ac[k], bb[k], acc_c, 0, 0, 0);
    }
    *reinterpret_cast<f32x4*>(&part[w][0][lane][0]) = acc_s;
    *reinterpret_cast<f32x4*>(&part[w][1][lane][0]) = acc_c;
    __syncthreads();

    if (t < 512) {
        const int c = t >> 4, il = t & 15;
        const int half = c >> 4, cl = c & 15;
        const int ln = ((cl >> 2) << 4) | il, rg = cl & 3;
        float s = 0.0f;
#pragma unroll
        for (int q = 0; q < 16; ++q) s += part[q][half][ln][rg];
        coup[c][il] = s;
    }
    __syncthreads();

    if (t < 256) {
        const int b2 = t >> 4;
        const int il = t & 15;
        const float aS = coup[b2][il];
        const float aC = coup[16 + b2][il];
        float nt = th_o + DT * (om_i + scale * (cos_i * aS - sin_i * aC));
        float ws, wc;
        sincosf(nt, &ws, &wc);
        th[o_upd] = FINAL ? atan2f(ws, wc) : nt;
        Rn[o_upd] = f2bf(ws);
        Rn[M_TOT + o_upd] = f2bf(wc);
    }
}

__global__ void coherence_kernel(const unsigned short* __restrict__ R,
                                 float* __restrict__ coh) {
    const int b = blockIdx.x;
    const int t = threadIdx.x;
    float ss = 0.0f, sc = 0.0f;
    for (int j = t; j < NOSC; j += 256) {
        ss += bf2f(R[(size_t)b * NOSC + j]);
        sc += bf2f(R[M_TOT + (size_t)b * NOSC + j]);
    }
    for (int off = 32; off > 0; off >>= 1) {
        ss += __shfl_down(ss, off);
        sc += __shfl_down(sc, off);
    }
    __shared__ float red[8];
    const int w = t >> 6;
    if ((t & 63) == 0) { red[w * 2] = sc; red[w * 2 + 1] = ss; }
    __syncthreads();
    if (t == 0) {
        float tc = 0.0f, ts = 0.0f;
        for (int k = 0; k < 4; ++k) { tc += red[k * 2]; ts += red[k * 2 + 1]; }
        tc /= (float)NOSC;
        ts /= (float)NOSC;
        coh[b] = sqrtf(tc * tc + ts * ts);
    }
}

extern "C" void kernel_launch(void* const* d_in, const int* in_sizes, int n_in,
                              void* d_out, int out_size, void* d_ws, size_t ws_size,
                              hipStream_t stream) {
    const float* theta_in = (const float*)d_in[0];
    const float* Kmat     = (const float*)d_in[1];
    const float* omega    = (const float*)d_in[2];
    const float* kg       = (const float*)d_in[3];
    const float* mod      = (const float*)d_in[4];

    float* th  = (float*)d_out;               // [NB][NOSC] final theta
    float* coh = (float*)d_out + M_TOT;       // [NB]

    // persistent-path control block at ws base (overlaps fallback's Kb — exclusive)
    unsigned int* cnt = (unsigned int*)d_ws;              // 11 u32
    float* accum = (float*)d_ws + 16;                     // 32 f32
    unsigned short* Kb = (unsigned short*)d_ws;           // 8 MB (fallback only)
    unsigned short* RA = (unsigned short*)d_ws + (size_t)NOSC * NOSC; // 128 KB
    unsigned short* RB = RA + 2 * M_TOT;                              // 128 KB

    zero_kernel<<<1, 64, 0, stream>>>(cnt, accum);

    void* args[] = {(void*)&theta_in, (void*)&Kmat, (void*)&omega,
                    (void*)&kg, (void*)&mod, (void*)&th, (void*)&coh,
                    (void*)&RA, (void*)&RB, (void*)&cnt, (void*)&accum};
    hipError_t err = hipLaunchCooperativeKernel((const void*)mega_kernel,
                                                dim3(NBLK_P), dim3(1024),
                                                args, 0, stream);
    if (err != hipSuccess) {
        // fallback: proven multi-dispatch path (overwrites cnt region as Kb)
        init_kernel<<<32, 256, 0, stream>>>(theta_in, th, RA);
        for (int s = 0; s < 10; ++s) {
            const unsigned short* rc = (s & 1) ? RB : RA;
            unsigned short* rn = (s & 1) ? RA : RB;
            if (s == 0)
                step_kernel<true, false><<<NOSC / 16, 1024, 0, stream>>>(
                    Kmat, Kb, rc, rn, omega, kg, mod, th);
            else if (s < 9)
                step_kernel<false, false><<<NOSC / 16, 1024, 0, stream>>>(
                    Kmat, Kb, rc, rn, omega, kg, mod, th);
            else
                step_kernel<false, true><<<NOSC / 16, 1024, 0, stream>>>(
                    Kmat, Kb, rc, rn, omega, kg, mod, th);
        }
        coherence_kernel<<<NB, 256, 0, stream>>>(RA, coh);
    }
}

// Round 15
// 104.609 us; speedup vs baseline: 5.3525x; 1.4051x over previous
//
#include <hip/hip_runtime.h>
#include <math.h>

#define NOSC 2048
#define NB 16
#define DT 0.1f
#define M_TOT (NB * NOSC)    // 32768
#define KTP 2056             // padded LDS K row
#define NBLK_P 128           // persistent blocks (1 per CU, half the GPU)

typedef __attribute__((ext_vector_type(8))) short bf16x8;
typedef __attribute__((ext_vector_type(4))) float f32x4;

__device__ __forceinline__ unsigned short f2bf(float x) {
    unsigned int u = __float_as_uint(x);
    u += 0x7FFFu + ((u >> 16) & 1u);          // round-to-nearest-even
    return (unsigned short)(u >> 16);
}
__device__ __forceinline__ float bf2f(unsigned short u) {
    return __uint_as_float(((unsigned int)u) << 16);
}

// fragment-tiled R layout: sin idx(c,j) = (j>>3)*128 + c*8 + (j&7); cos +M_TOT.
// Wave w's MFMA A-fragment k = contiguous [w*2048 + k*512 + lane*8 .. +8) shorts.
__device__ __forceinline__ int ridx(int c, int j) {
    return ((j >> 3) << 7) + (c << 3) + (j & 7);
}

// ---- agent-scope RELAXED helpers (sc1: bypass L2, coherent at L3; no fences) ----
__device__ __forceinline__ bf16x8 loadR16(const unsigned short* p) {
    union { unsigned long long u[2]; bf16x8 v; } x;
    x.u[0] = __hip_atomic_load((const unsigned long long*)p,
                               __ATOMIC_RELAXED, __HIP_MEMORY_SCOPE_AGENT);
    x.u[1] = __hip_atomic_load((const unsigned long long*)p + 1,
                               __ATOMIC_RELAXED, __HIP_MEMORY_SCOPE_AGENT);
    return x.v;
}
__device__ __forceinline__ void storeU32(unsigned short* p, unsigned int v) {
    __hip_atomic_store((unsigned int*)p, v,
                       __ATOMIC_RELAXED, __HIP_MEMORY_SCOPE_AGENT);
}

// Fence-free grid barrier (round 14, proven): release = vmcnt(0) drain;
// arrival/poll = RELAXED agent atomics (no buffer_inv / wbl2 storms).
__device__ __forceinline__ void gbar(unsigned int* cnt, int t) {
    asm volatile("s_waitcnt vmcnt(0)" ::: "memory");
    __syncthreads();
    if (t == 0) {
        __hip_atomic_fetch_add(cnt, 1u, __ATOMIC_RELAXED, __HIP_MEMORY_SCOPE_AGENT);
        while (__hip_atomic_load(cnt, __ATOMIC_RELAXED, __HIP_MEMORY_SCOPE_AGENT) < NBLK_P)
            __builtin_amdgcn_s_sleep(1);
    }
    __syncthreads();
}

// ws layout:
//   persistent path: [cnt 11 u32][pad][accum 32 f32] at base
//   fallback path:   Kb[2048][2048] bf16 at base (8 MB) — paths never coexist
//   both: RA / RB bf16 R-buffers at base + 8 MB (128 KB each)

__global__ void zero_kernel(unsigned int* cnt, float* accum) {
    const int t = threadIdx.x;
    if (t < 11) cnt[t] = 0u;
    if (t < 32) accum[t] = 0.0f;
}

// ---------------- persistent cooperative kernel ----------------
// 128 blocks x 1024 thr. Block owns i in [bx*16, bx*16+16).
// K tile in LDS for ALL steps; theta/sin/cos in registers; R via L3 atomics
// in the fragment-tiled layout (coalesced 1 KB/wave sc1 loads).
__global__ __launch_bounds__(1024, 4) void mega_kernel(
    const float* __restrict__ theta_in,
    const float* __restrict__ Kmat,
    const float* __restrict__ omega,
    const float* __restrict__ kg,
    const float* __restrict__ mod,
    float* __restrict__ th,
    float* __restrict__ coh,
    unsigned short* __restrict__ RA,
    unsigned short* __restrict__ RB,
    unsigned int* __restrict__ cnt,
    float* __restrict__ accum)
{
    __shared__ unsigned short Kt[16][KTP];          // 64.25 KB, persistent
    __shared__ float part[16][2][64][4];            // 32 KB
    __shared__ float coup[32][16];                  // 2 KB

    const int t = threadIdx.x;
    const int lane = t & 63;
    const int w = t >> 6;                            // wave = k-sixteenth
    const int i0 = blockIdx.x * 16;
    const int rl = lane & 15;
    const int kbase = w * 128 + ((lane >> 4) << 3);

    // ---- one-time: convert own K tile (16 rows, 128 KB fp32 contiguous) to LDS
    {
        const float4* __restrict__ src =
            reinterpret_cast<const float4*>(Kmat + (size_t)i0 * NOSC);
#pragma unroll
        for (int p = 0; p < 8; ++p) {
            const int q = t + p * 1024;              // float4 index 0..8191
            float4 v = src[q];
            ushort4 u = {f2bf(v.x), f2bf(v.y), f2bf(v.z), f2bf(v.w)};
            *reinterpret_cast<ushort4*>(&Kt[q >> 9][(q & 511) * 4]) = u;
        }
    }

    // ---- one-time: own theta state into registers, publish R0 (tiled layout)
    float th_o = 0.0f, sin_i = 0.0f, cos_i = 0.0f, om_i = 0.0f;
    float ws = 0.0f, wc = 0.0f;
    size_t o_upd = 0; int b2 = 0, il = 0, Lr = 0;
    if (t < 256) {
        b2 = t >> 4; il = t & 15;
        o_upd = (size_t)b2 * NOSC + i0 + il;
        Lr = ridx(b2, i0 + il);
        om_i = omega[i0 + il];
        th_o = theta_in[o_upd];
        sincosf(th_o, &sin_i, &cos_i);
        float sn = __shfl_down(sin_i, 1), cn = __shfl_down(cos_i, 1);
        if ((il & 1) == 0) {
            storeU32(RA + Lr, (unsigned)f2bf(sin_i) | ((unsigned)f2bf(sn) << 16));
            storeU32(RA + M_TOT + Lr, (unsigned)f2bf(cos_i) | ((unsigned)f2bf(cn) << 16));
        }
    }
    const float scale = kg[0] * (1.0f + mod[0]) * (1.0f / (float)NOSC);

    gbar(&cnt[0], t);           // R0 complete everywhere

    const unsigned short* Rcur = RA;
    unsigned short* Rnxt = RB;

    for (int s = 0; s < 10; ++s) {
        // A fragments: tiled layout -> lane-contiguous 16 B, dense 1 KB/wave
        bf16x8 as[4], ac[4], bb[4];
        const unsigned short* pa = Rcur + (w << 11) + (lane << 3);
#pragma unroll
        for (int k = 0; k < 4; ++k) {
            as[k] = loadR16(pa + (k << 9));
            ac[k] = loadR16(pa + M_TOT + (k << 9));
            bb[k] = *reinterpret_cast<const bf16x8*>(&Kt[rl][kbase + k * 32]);
        }
        f32x4 acc_s = {0.0f, 0.0f, 0.0f, 0.0f};
        f32x4 acc_c = {0.0f, 0.0f, 0.0f, 0.0f};
#pragma unroll
        for (int k = 0; k < 4; ++k) {
            acc_s = __builtin_amdgcn_mfma_f32_16x16x32_bf16(as[k], bb[k], acc_s, 0, 0, 0);
            acc_c = __builtin_amdgcn_mfma_f32_16x16x32_bf16(ac[k], bb[k], acc_c, 0, 0, 0);
        }
        *reinterpret_cast<f32x4*>(&part[w][0][lane][0]) = acc_s;
        *reinterpret_cast<f32x4*>(&part[w][1][lane][0]) = acc_c;
        __syncthreads();

        if (t < 512) {                               // reduce 16 k-partials
            const int c = t >> 4, ilr = t & 15;
            const int half = c >> 4, cl = c & 15;
            const int ln = ((cl >> 2) << 4) | ilr, rg = cl & 3;
            float sum = 0.0f;
#pragma unroll
            for (int q = 0; q < 16; ++q) sum += part[q][half][ln][rg];
            coup[c][ilr] = sum;
        }
        __syncthreads();

        if (t < 256) {                               // theta update (in-register)
            const float aS = coup[b2][il];
            const float aC = coup[16 + b2][il];
            float nt = th_o + DT * (om_i + scale * (cos_i * aS - sin_i * aC));
            sincosf(nt, &ws, &wc);
            if (s == 9) {
                th[o_upd] = atan2f(ws, wc);          // final wrap to (-pi, pi]
            } else {
                // wrap only shifts by 2*pi*k -> sin/cos unchanged; defer atan2
                th_o = nt; sin_i = ws; cos_i = wc;
                float sn = __shfl_down(ws, 1), cn = __shfl_down(wc, 1);
                if ((il & 1) == 0) {
                    storeU32(Rnxt + Lr, (unsigned)f2bf(ws) | ((unsigned)f2bf(sn) << 16));
                    storeU32(Rnxt + M_TOT + Lr, (unsigned)f2bf(wc) | ((unsigned)f2bf(cn) << 16));
                }
            }
        }
        if (s < 9) {
            gbar(&cnt[s + 1], t);
            const unsigned short* tmp = Rcur;
            Rcur = Rnxt; Rnxt = (unsigned short*)tmp;
        }
    }

    // ---- fused coherence: sum final ws/wc over this block's 16 i per batch
    if (t < 256) {
#pragma unroll
        for (int m = 1; m < 16; m <<= 1) {
            ws += __shfl_xor(ws, m);
            wc += __shfl_xor(wc, m);
        }
        if (il == 0) {
            __hip_atomic_fetch_add(&accum[b2], ws, __ATOMIC_RELAXED, __HIP_MEMORY_SCOPE_AGENT);
            __hip_atomic_fetch_add(&accum[16 + b2], wc, __ATOMIC_RELAXED, __HIP_MEMORY_SCOPE_AGENT);
        }
    }
    gbar(&cnt[10], t);
    if (blockIdx.x == 0 && t < 16) {
        float ss = __hip_atomic_load(&accum[t], __ATOMIC_RELAXED, __HIP_MEMORY_SCOPE_AGENT)
                   * (1.0f / (float)NOSC);
        float cc = __hip_atomic_load(&accum[16 + t], __ATOMIC_RELAXED, __HIP_MEMORY_SCOPE_AGENT)
                   * (1.0f / (float)NOSC);
        coh[t] = sqrtf(ss * ss + cc * cc);
    }
}

// ---------------- fallback: multi-dispatch path (row-major R, self-consistent) ----------------
__global__ void init_kernel(const float* __restrict__ th_in,
                            float* __restrict__ th,
                            unsigned short* __restrict__ R0) {
    const int o4 = (blockIdx.x * 256 + threadIdx.x) * 4;
    if (o4 < M_TOT) {
        float4 v = *reinterpret_cast<const float4*>(th_in + o4);
        *reinterpret_cast<float4*>(th + o4) = v;
        float s0, c0, s1, c1, s2, c2, s3, c3;
        sincosf(v.x, &s0, &c0); sincosf(v.y, &s1, &c1);
        sincosf(v.z, &s2, &c2); sincosf(v.w, &s3, &c3);
        ushort4 us = {f2bf(s0), f2bf(s1), f2bf(s2), f2bf(s3)};
        ushort4 uc = {f2bf(c0), f2bf(c1), f2bf(c2), f2bf(c3)};
        *reinterpret_cast<ushort4*>(R0 + o4) = us;
        *reinterpret_cast<ushort4*>(R0 + M_TOT + o4) = uc;
    }
}

template <bool FIRST, bool FINAL>
__global__ __launch_bounds__(1024, 4) void step_kernel(
    const float* __restrict__ Kmat,
    unsigned short* __restrict__ Kb,
    const unsigned short* __restrict__ Rc,
    unsigned short* __restrict__ Rn,
    const float* __restrict__ omega,
    const float* __restrict__ kg,
    const float* __restrict__ mod,
    float* __restrict__ th)
{
    __shared__ float part[16][2][64][4];
    __shared__ float coup[32][16];

    const int t = threadIdx.x;
    const int lane = t & 63;
    const int w = t >> 6;
    const int i0 = blockIdx.x * 16;

    float th_o = 0.0f, sin_i = 0.0f, cos_i = 0.0f, om_i = 0.0f;
    size_t o_upd = 0;
    if (t < 256) {
        const int b2 = t >> 4;
        const int il = t & 15;
        o_upd = (size_t)b2 * NOSC + i0 + il;
        th_o = th[o_upd];
        sin_i = bf2f(Rc[o_upd]);
        cos_i = bf2f(Rc[M_TOT + o_upd]);
        om_i = omega[i0 + il];
    }
    const float scale = kg[0] * (1.0f + mod[0]) * (1.0f / (float)NOSC);

    const int rl = lane & 15;
    const int kbase = w * 128 + ((lane >> 4) << 3);
    const unsigned short* __restrict__ pas = Rc + (size_t)rl * NOSC + kbase;
    const unsigned short* __restrict__ pac = Rc + (size_t)(16 + rl) * NOSC + kbase;

    bf16x8 as[4], ac[4], bb[4];
    if constexpr (FIRST) {
        __shared__ unsigned short Kt[16][KTP];
        const float4* __restrict__ src =
            reinterpret_cast<const float4*>(Kmat + (size_t)i0 * NOSC);
#pragma unroll
        for (int p = 0; p < 8; ++p) {
            const int q = t + p * 1024;
            float4 v = src[q];
            ushort4 u = {f2bf(v.x), f2bf(v.y), f2bf(v.z), f2bf(v.w)};
            const int row = q >> 9;
            const int col = (q & 511) * 4;
            *reinterpret_cast<ushort4*>(&Kt[row][col]) = u;
            *reinterpret_cast<ushort4*>(Kb + (size_t)(i0 + row) * NOSC + col) = u;
        }
        __syncthreads();
#pragma unroll
        for (int k = 0; k < 4; ++k)
            bb[k] = *reinterpret_cast<const bf16x8*>(&Kt[rl][kbase + k * 32]);
    } else {
        const unsigned short* __restrict__ pbg = Kb + (size_t)(i0 + rl) * NOSC + kbase;
#pragma unroll
        for (int k = 0; k < 4; ++k)
            bb[k] = *reinterpret_cast<const bf16x8*>(pbg + k * 32);
    }
#pragma unroll
    for (int k = 0; k < 4; ++k) {
        as[k] = *reinterpret_cast<const bf16x8*>(pas + k * 32);
        ac[k] = *reinterpret_cast<const bf16x8*>(pac + k * 32);
    }

    f32x4 acc_s = {0.0f, 0.0f, 0.0f, 0.0f};
    f32x4 acc_c = {0.0f, 0.0f, 0.0f, 0.0f};
#pragma unroll
    for (int k = 0; k < 4; ++k) {
        acc_s = __builtin_amdgcn_mfma_f32_16x16x32_bf16(as[k], bb[k], acc_s, 0, 0, 0);
        acc_c = __builtin_amdgcn_mfma_f32_16x16x32_bf16(ac[k], bb[k], acc_c, 0, 0, 0);
    }
    *reinterpret_cast<f32x4*>(&part[w][0][lane][0]) = acc_s;
    *reinterpret_cast<f32x4*>(&part[w][1][lane][0]) = acc_c;
    __syncthreads();

    if (t < 512) {
        const int c = t >> 4, il = t & 15;
        const int half = c >> 4, cl = c & 15;
        const int ln = ((cl >> 2) << 4) | il, rg = cl & 3;
        float s = 0.0f;
#pragma unroll
        for (int q = 0; q < 16; ++q) s += part[q][half][ln][rg];
        coup[c][il] = s;
    }
    __syncthreads();

    if (t < 256) {
        const int b2 = t >> 4;
        const int il = t & 15;
        const float aS = coup[b2][il];
        const float aC = coup[16 + b2][il];
        float nt = th_o + DT * (om_i + scale * (cos_i * aS - sin_i * aC));
        float ws, wc;
        sincosf(nt, &ws, &wc);
        th[o_upd] = FINAL ? atan2f(ws, wc) : nt;
        Rn[o_upd] = f2bf(ws);
        Rn[M_TOT + o_upd] = f2bf(wc);
    }
}

__global__ void coherence_kernel(const unsigned short* __restrict__ R,
                                 float* __restrict__ coh) {
    const int b = blockIdx.x;
    const int t = threadIdx.x;
    float ss = 0.0f, sc = 0.0f;
    for (int j = t; j < NOSC; j += 256) {
        ss += bf2f(R[(size_t)b * NOSC + j]);
        sc += bf2f(R[M_TOT + (size_t)b * NOSC + j]);
    }
    for (int off = 32; off > 0; off >>= 1) {
        ss += __shfl_down(ss, off);
        sc += __shfl_down(sc, off);
    }
    __shared__ float red[8];
    const int w = t >> 6;
    if ((t & 63) == 0) { red[w * 2] = sc; red[w * 2 + 1] = ss; }
    __syncthreads();
    if (t == 0) {
        float tc = 0.0f, ts = 0.0f;
        for (int k = 0; k < 4; ++k) { tc += red[k * 2]; ts += red[k * 2 + 1]; }
        tc /= (float)NOSC;
        ts /= (float)NOSC;
        coh[b] = sqrtf(tc * tc + ts * ts);
    }
}

extern "C" void kernel_launch(void* const* d_in, const int* in_sizes, int n_in,
                              void* d_out, int out_size, void* d_ws, size_t ws_size,
                              hipStream_t stream) {
    const float* theta_in = (const float*)d_in[0];
    const float* Kmat     = (const float*)d_in[1];
    const float* omega    = (const float*)d_in[2];
    const float* kg       = (const float*)d_in[3];
    const float* mod      = (const float*)d_in[4];

    float* th  = (float*)d_out;               // [NB][NOSC] final theta
    float* coh = (float*)d_out + M_TOT;       // [NB]

    // persistent-path control block at ws base (overlaps fallback's Kb — exclusive)
    unsigned int* cnt = (unsigned int*)d_ws;              // 11 u32
    float* accum = (float*)d_ws + 16;                     // 32 f32
    unsigned short* Kb = (unsigned short*)d_ws;           // 8 MB (fallback only)
    unsigned short* RA = (unsigned short*)d_ws + (size_t)NOSC * NOSC; // 128 KB
    unsigned short* RB = RA + 2 * M_TOT;                              // 128 KB

    zero_kernel<<<1, 64, 0, stream>>>(cnt, accum);

    void* args[] = {(void*)&theta_in, (void*)&Kmat, (void*)&omega,
                    (void*)&kg, (void*)&mod, (void*)&th, (void*)&coh,
                    (void*)&RA, (void*)&RB, (void*)&cnt, (void*)&accum};
    hipError_t err = hipLaunchCooperativeKernel((const void*)mega_kernel,
                                                dim3(NBLK_P), dim3(1024),
                                                args, 0, stream);
    if (err != hipSuccess) {
        // fallback: proven multi-dispatch path (overwrites cnt region as Kb)
        init_kernel<<<32, 256, 0, stream>>>(theta_in, th, RA);
        for (int s = 0; s < 10; ++s) {
            const unsigned short* rc = (s & 1) ? RB : RA;
            unsigned short* rn = (s & 1) ? RA : RB;
            if (s == 0)
                step_kernel<true, false><<<NOSC / 16, 1024, 0, stream>>>(
                    Kmat, Kb, rc, rn, omega, kg, mod, th);
            else if (s < 9)
                step_kernel<false, false><<<NOSC / 16, 1024, 0, stream>>>(
                    Kmat, Kb, rc, rn, omega, kg, mod, th);
            else
                step_kernel<false, true><<<NOSC / 16, 1024, 0, stream>>>(
                    Kmat, Kb, rc, rn, omega, kg, mod, th);
        }
        coherence_kernel<<<NB, 256, 0, stream>>>(RA, coh);
    }
}